// Round 11
// baseline (169.160 us; speedup 1.0000x reference)
//
#include <hip/hip_runtime.h>
#include <stdint.h>
#include <stddef.h>

// Attention_50886772523162: x[2,2048,1024] -> causal MHA (16 heads, hd=64) -> out
// dtype (fp32 vs bf16) detected at runtime; compute bf16 MFMA, fp32 accum.
// Pipeline: detect -> convert x -> transpose weights (Wq|Wkv fused) ->
//           QKV proj (one GEMM) -> flash attn (balanced strips + KV-parity
//           split, 2048 waves = 2/SIMD) -> combine partials -> O proj.
// NOTE: raw v_permlane32_swap_b32 inline asm caused NaN (R5) — blacklisted.
// NOTE: K direct-from-global (R7) regressed 2x — keep cooperative staging.
// NOTE: R8: causal imbalance => complementary strips (P, 63-P).
// NOTE: R9/R10: waves/SIMD is set by TOTAL wave count (q-rows/strip-rows/2);
//       at 1024 waves half the SIMDs idle. KV-split doubles waves to 2048.

typedef __bf16 bf16;
typedef __bf16 bf16x8 __attribute__((ext_vector_type(8)));
typedef __bf16 bf16x4 __attribute__((ext_vector_type(4)));
typedef __bf16 bf16x2 __attribute__((ext_vector_type(2)));
typedef float  f32x4  __attribute__((ext_vector_type(4)));
typedef float  f32x16 __attribute__((ext_vector_type(16)));

#define NSEQ 2048
#define DM   1024
#define HD   64
#define QKVS 3072          // fused QKV row stride
#define LOG2E 1.44269504f

#define GLD16(g, l) __builtin_amdgcn_global_load_lds(                         \
    (const __attribute__((address_space(1))) void*)(g),                       \
    (__attribute__((address_space(3))) void*)(l), 16, 0, 0)

// ---------------- dtype detection ----------------
__global__ void detect_dtype(const uint32_t* __restrict__ x, int* __restrict__ flag) {
  __shared__ int cnt;
  if (threadIdx.x == 0) cnt = 0;
  __syncthreads();
  int c = 0;
  for (int i = threadIdx.x; i < 4096; i += 256) {
    uint32_t e = (x[i] >> 7) & 0xFF;
    if (e >= 110 && e <= 132) c++;
  }
  atomicAdd(&cnt, c);
  __syncthreads();
  if (threadIdx.x == 0) *flag = (cnt > 2048) ? 1 : 0;   // 1 = bf16 data
}

// ---------------- x -> canonical bf16 ----------------
__global__ __launch_bounds__(256) void convert_x(
    const void* __restrict__ in, bf16* __restrict__ out, int n,
    const int* __restrict__ flagp) {
  const int flag = *flagp;
  const int i = (blockIdx.x * 256 + threadIdx.x) * 8;
  if (i >= n) return;
  if (flag) {
    *(bf16x8*)(out + i) = *(const bf16x8*)((const bf16*)in + i);
  } else {
    const float* f = (const float*)in;
    bf16x8 v;
#pragma unroll
    for (int e = 0; e < 8; ++e) v[e] = (bf16)f[i + e];
    *(bf16x8*)(out + i) = v;
  }
}

// ---------------- weight transpose(+convert): in[K][N] -> out[N][K] ----------------
__global__ void transpose_conv(const void* __restrict__ in, bf16* __restrict__ out,
                               int K, int N, const int* __restrict__ flagp) {
  __shared__ bf16 tile[32][33];
  const int flag = *flagp;
  const int k0 = blockIdx.y * 32, n0 = blockIdx.x * 32;
  const int tx = threadIdx.x, ty = threadIdx.y;
  if (flag) {
    const bf16* p = (const bf16*)in;
#pragma unroll
    for (int i = ty; i < 32; i += 8)
      tile[i][tx] = p[(size_t)(k0 + i) * N + n0 + tx];
  } else {
    const float* p = (const float*)in;
#pragma unroll
    for (int i = ty; i < 32; i += 8)
      tile[i][tx] = (bf16)p[(size_t)(k0 + i) * N + n0 + tx];
  }
  __syncthreads();
#pragma unroll
  for (int i = ty; i < 32; i += 8)
    out[(size_t)(n0 + i) * K + k0 + tx] = tile[tx][i];
}

// ---------------- GEMM: C[M][N] = A[M][K] * Bt[N][K]^T ----------------
// 128x128 tile, BK=64, 4 waves (2x2), mfma_f32_16x16x32_bf16.
// Staging via global_load_lds (16B/lane, linear LDS dest, pre-swizzled source).
__global__ __launch_bounds__(256) void gemm_bt(
    const bf16* __restrict__ A, const bf16* __restrict__ Bt,
    void* __restrict__ C, int M, int N, int K, const int* flagp)
{
  __shared__ bf16 As[128][64];
  __shared__ bf16 Bs[128][64];
  const int tid  = threadIdx.x;
  const int wave = tid >> 6, lane = tid & 63;
  const int fr = lane & 15, fg = lane >> 4;
  const int m0 = blockIdx.y * 128, n0 = blockIdx.x * 128;
  const int wr = (wave >> 1) * 64, wc = (wave & 1) * 64;
  const int lrow = lane >> 3;                    // row within 8-row chunk
  const int lcol = 8 * ((lane & 7) ^ lrow);      // pre-swizzled source col (elems)

  f32x4 acc[4][4] = {};

  for (int kt = 0; kt < K; kt += 64) {
    __syncthreads();                              // protect prev-iter reads
#pragma unroll
    for (int p = 0; p < 4; ++p) {
      const int chunk = wave * 4 + p;             // 8 rows per chunk
      const int r = chunk * 8 + lrow;
      GLD16(A  + (size_t)(m0 + r) * K + kt + lcol, &As[chunk * 8][0]);
      GLD16(Bt + (size_t)(n0 + r) * K + kt + lcol, &Bs[chunk * 8][0]);
    }
    __syncthreads();                              // vmcnt(0) drain + barrier
#pragma unroll
    for (int s = 0; s < 2; ++s) {
      bf16x8 af[4], bfr[4];
#pragma unroll
      for (int i = 0; i < 4; ++i) {
        const int ar = wr + i * 16 + fr;
        af[i]  = *(const bf16x8*)((const char*)&As[ar][0] +
                   ((s * 64 + fg * 16) ^ ((ar & 7) << 4)));
        const int br = wc + i * 16 + fr;
        bfr[i] = *(const bf16x8*)((const char*)&Bs[br][0] +
                   ((s * 64 + fg * 16) ^ ((br & 7) << 4)));
      }
#pragma unroll
      for (int i = 0; i < 4; ++i)
#pragma unroll
        for (int j = 0; j < 4; ++j)
          acc[i][j] = __builtin_amdgcn_mfma_f32_16x16x32_bf16(
              af[i], bfr[j], acc[i][j], 0, 0, 0);
    }
  }
  const int crow = m0 + wr + fg * 4;
  const int ccol = n0 + wc + fr;
  const int as_bf16 = flagp ? *flagp : 1;
  if (as_bf16) {
    bf16* Cb = (bf16*)C;
#pragma unroll
    for (int i = 0; i < 4; ++i)
#pragma unroll
      for (int j = 0; j < 4; ++j)
#pragma unroll
        for (int r = 0; r < 4; ++r)
          Cb[(size_t)(crow + i * 16 + r) * N + ccol + j * 16] = (bf16)acc[i][j][r];
  } else {
    float* Cf = (float*)C;
#pragma unroll
    for (int i = 0; i < 4; ++i)
#pragma unroll
      for (int j = 0; j < 4; ++j)
#pragma unroll
        for (int r = 0; r < 4; ++r)
          Cf[(size_t)(crow + i * 16 + r) * N + ccol + j * 16] = acc[i][j][r];
  }
}

// ---------------- causal flash attention, balanced strips + KV split ----------
// QKV: [B*N][3072] rows = (Q | K | V), head col offset hi*64.
// Block = 2 waves (128 threads); grid 16 pairs x 32 bh x 2 kv-parity.
// Wave owns strips sA = 2*pair+wave and sB = 63-sA; z handles tiles j = z,z+2,..
// Outputs UNNORMALIZED partial O (bf16) + (m,l) per q-row; combined later.
static __device__ inline uint32_t pk2(float a, float b) {
  bf16x2 t; t[0] = (bf16)a; t[1] = (bf16)b;
  return __builtin_bit_cast(uint32_t, t);
}

// One strip x one KV tile (R8/R9-verified compute core).
static __device__ __forceinline__ void strip_tile(
    const bf16 (&Ksb)[64][64], const bf16 (&Vtb)[64][64],
    const bf16x8 (&qf)[4], f32x16 (&oacc)[2], float& m, float& l,
    const int j0, const int q0, const int c, const int h)
{
  const int qrow = q0 + c;
  const int blkmax = (j0 + 32 <= q0 + 31) ? 2 : 1;

  f32x16 sv[2];
  __builtin_amdgcn_s_setprio(1);
#pragma unroll
  for (int blk = 0; blk < 2; ++blk)
    if (blk < blkmax) {
      f32x16 a = {};
#pragma unroll
      for (int ks = 0; ks < 4; ++ks) {
        const int krow = blk * 32 + c;
        bf16x8 kf = *(const bf16x8*)((const char*)&Ksb[krow][0] +
                     ((ks * 32 + h * 16) ^ ((krow & 7) << 4)));
        a = __builtin_amdgcn_mfma_f32_32x32x16_bf16(kf, qf[ks], a, 0, 0, 0);
      }
      sv[blk] = a;
    }
  __builtin_amdgcn_s_setprio(0);

  if (j0 + 63 > q0) {                       // causal mask (raw-S domain)
#pragma unroll
    for (int blk = 0; blk < 2; ++blk)
      if (blk < blkmax) {
        const int kvb = j0 + blk * 32 + 4 * h;
#pragma unroll
        for (int r = 0; r < 16; ++r) {
          const int kv = kvb + (r & 3) + 8 * (r >> 2);
          if (kv > qrow) sv[blk][r] = -4.0e8f;
        }
      }
  }

  // online softmax, lane-local; defer-max (T13, THR=8)
  float tmax = -3.0e38f;
#pragma unroll
  for (int blk = 0; blk < 2; ++blk)
    if (blk < blkmax)
#pragma unroll
      for (int r = 0; r < 16; ++r) tmax = fmaxf(tmax, sv[blk][r]);
  tmax = fmaxf(tmax, __shfl_xor(tmax, 32));
  const float pmax = tmax * 0.125f;
  if (!__all(pmax - m <= 8.0f)) {
    const float mnew  = fmaxf(m, pmax);
    const float alpha = __builtin_amdgcn_exp2f((m - mnew) * LOG2E);
    m = mnew;
    l *= alpha;
#pragma unroll
    for (int db = 0; db < 2; ++db)
#pragma unroll
      for (int r = 0; r < 16; ++r) oacc[db][r] *= alpha;
  }
  const float km = 0.125f * LOG2E, kb = -m * LOG2E;
  float sum = 0.f;
#pragma unroll
  for (int blk = 0; blk < 2; ++blk)
    if (blk < blkmax)
#pragma unroll
      for (int r = 0; r < 16; ++r) {
        const float p = __builtin_amdgcn_exp2f(__builtin_fmaf(sv[blk][r], km, kb));
        sv[blk][r] = p;
        sum += p;
      }
  sum += __shfl_xor(sum, 32);
  l += sum;

  // P redistribution (D-layout -> B-operand) + PV
#pragma unroll
  for (int blk = 0; blk < 2; ++blk)
    if (blk < blkmax) {
      uint32_t w[8], xw[8];
#pragma unroll
      for (int g = 0; g < 4; ++g) {
        w[2 * g]     = pk2(sv[blk][4 * g],     sv[blk][4 * g + 1]);
        w[2 * g + 1] = pk2(sv[blk][4 * g + 2], sv[blk][4 * g + 3]);
      }
#pragma unroll
      for (int i = 0; i < 8; ++i)
        xw[i] = (uint32_t)__shfl_xor((int)w[i], 32);
#pragma unroll
      for (int ks = 0; ks < 2; ++ks) {
        union { uint32_t u[4]; bf16x8 v; } pf;
        pf.u[0] = h ? xw[4 * ks + 2] : w[4 * ks];
        pf.u[1] = h ? xw[4 * ks + 3] : w[4 * ks + 1];
        pf.u[2] = h ? w[4 * ks + 2]  : xw[4 * ks];
        pf.u[3] = h ? w[4 * ks + 3]  : xw[4 * ks + 1];
        __builtin_amdgcn_s_setprio(1);
#pragma unroll
        for (int db = 0; db < 2; ++db) {
          const int vrow = db * 32 + c;
          bf16x8 vf = *(const bf16x8*)((const char*)&Vtb[vrow][0] +
                       ((blk * 64 + ks * 32 + h * 16) ^ ((vrow & 7) << 4)));
          oacc[db] = __builtin_amdgcn_mfma_f32_32x32x16_bf16(vf, pf.v, oacc[db], 0, 0, 0);
        }
        __builtin_amdgcn_s_setprio(0);
      }
    }
}

__global__ __launch_bounds__(128) void attn_fwd(
    const bf16* __restrict__ QKV, bf16* __restrict__ O0, bf16* __restrict__ O1,
    float2* __restrict__ mlbuf)
{
  __shared__ bf16 Ks[2][64][64];   // K tiles [kv][d], rows XOR-swizzled
  __shared__ bf16 Vt[2][64][64];   // V^T tiles [d][kv], rows XOR-swizzled

  const int pr = blockIdx.x;       // pair index 0..15
  const int bh = blockIdx.y;
  const int z  = blockIdx.z;       // KV parity 0/1
  const int bi = bh >> 4, hi = bh & 15;
  const int tid = threadIdx.x, wave = tid >> 6, lane = tid & 63;
  const int c = lane & 31, h = lane >> 5;

  const bf16* qptr = QKV + (size_t)bi * NSEQ * QKVS + hi * HD;
  const bf16* kptr = qptr + DM;
  const bf16* vptr = qptr + 2 * DM;

  // complementary strips (32 q-rows each)
  const int sA = 2 * pr + wave, sB = 63 - sA;
  const int q0A = sA * 32, q0B = sB * 32;

  bf16x8 qfA[4], qfB[4];
#pragma unroll
  for (int ks = 0; ks < 4; ++ks) {
    qfA[ks] = *(const bf16x8*)(qptr + (size_t)(q0A + c) * QKVS + ks * 16 + h * 8);
    qfB[ks] = *(const bf16x8*)(qptr + (size_t)(q0B + c) * QKVS + ks * 16 + h * 8);
  }

  f32x16 oaccA[2] = {}, oaccB[2] = {};
  float mA = -1e30f, lA = 0.f, mB = -1e30f, lB = 0.f;

  // K staging: 128 threads cover 16 rows x 8 chunks per pass, 4 passes
  const int srow = tid >> 3, sch = tid & 7;
  const int koff = (sch * 16) ^ ((srow & 7) << 4);   // (row+16p)&7 == row&7
  // V staging: thread covers 4 kv rows x 8 d cols (64x64 in one pass)
  const int kvg = (tid & 15) * 4, dg = (tid >> 4) * 8;

  bf16x8 kpre[4], vpre[4];      // prefetch regs

  const int ntil = 32 - pr;     // tiles covering strip B (the larger)

  // prologue: tile z -> LDS buf0 directly; tile z+2 -> regs
  {
    const size_t jz = (size_t)(z * 64);
#pragma unroll
    for (int p = 0; p < 4; ++p)
      kpre[p] = *(const bf16x8*)(kptr + (jz + srow + 16 * p) * QKVS + sch * 8);
#pragma unroll
    for (int i = 0; i < 4; ++i)
      vpre[i] = *(const bf16x8*)(vptr + (jz + kvg + i) * QKVS + dg);
#pragma unroll
    for (int p = 0; p < 4; ++p)
      *(bf16x8*)((char*)&Ks[0][srow + 16 * p][0] + koff) = kpre[p];
#pragma unroll
    for (int e = 0; e < 8; ++e) {
      const int d = dg + e;
      bf16x4 w; w[0] = vpre[0][e]; w[1] = vpre[1][e];
      w[2] = vpre[2][e]; w[3] = vpre[3][e];
      *(bf16x4*)((char*)&Vt[0][d][0] + ((2 * kvg) ^ ((d & 7) << 4))) = w;
    }
    if (z + 2 < ntil) {
      const size_t jn = (size_t)((z + 2) * 64);
#pragma unroll
      for (int p = 0; p < 4; ++p)
        kpre[p] = *(const bf16x8*)(kptr + (jn + srow + 16 * p) * QKVS + sch * 8);
#pragma unroll
      for (int i = 0; i < 4; ++i)
        vpre[i] = *(const bf16x8*)(vptr + (jn + kvg + i) * QKVS + dg);
    }
  }
  __syncthreads();

  int cur = 0;
  for (int j = z; j < ntil; j += 2) {
    const int j0 = j * 64;

    // top: publish tile j+2 into the other buffer
    if (j + 2 < ntil) {
      const int nb = cur ^ 1;
#pragma unroll
      for (int p = 0; p < 4; ++p)
        *(bf16x8*)((char*)&Ks[nb][srow + 16 * p][0] + koff) = kpre[p];
#pragma unroll
      for (int e = 0; e < 8; ++e) {
        const int d = dg + e;
        bf16x4 w; w[0] = vpre[0][e]; w[1] = vpre[1][e];
        w[2] = vpre[2][e]; w[3] = vpre[3][e];
        *(bf16x4*)((char*)&Vt[nb][d][0] + ((2 * kvg) ^ ((d & 7) << 4))) = w;
      }
    }
    // issue tile j+4 loads (land during next iteration's compute)
    if (j + 4 < ntil) {
      const size_t jn = (size_t)((j + 4) * 64);
#pragma unroll
      for (int p = 0; p < 4; ++p)
        kpre[p] = *(const bf16x8*)(kptr + (jn + srow + 16 * p) * QKVS + sch * 8);
#pragma unroll
      for (int i = 0; i < 4; ++i)
        vpre[i] = *(const bf16x8*)(vptr + (jn + kvg + i) * QKVS + dg);
    }

    // strip B (large) and strip A (small), activity wave-uniform
    if (j0 <= q0B + 31)
      strip_tile(Ks[cur], Vt[cur], qfB, oaccB, mB, lB, j0, q0B, c, h);
    if (j0 <= q0A + 31)
      strip_tile(Ks[cur], Vt[cur], qfA, oaccA, mA, lA, j0, q0A, c, h);

    __syncthreads();              // single barrier per tile
    cur ^= 1;
  }

  // epilogue: write UNNORMALIZED partial O + (m,l) per q-row
  bf16* Op = z ? O1 : O0;
#pragma unroll
  for (int sidx = 0; sidx < 2; ++sidx) {
    const f32x16* oacc = sidx ? oaccB : oaccA;
    const int q0 = sidx ? q0B : q0A;
    bf16* obase = Op + (size_t)bi * NSEQ * DM + (size_t)hi * HD +
                  (size_t)(q0 + c) * DM;
#pragma unroll
    for (int db = 0; db < 2; ++db)
#pragma unroll
      for (int g = 0; g < 4; ++g) {
        bf16x4 ov;
#pragma unroll
        for (int jj = 0; jj < 4; ++jj) ov[jj] = (bf16)oacc[db][4 * g + jj];
        *(bf16x4*)(obase + db * 32 + 8 * g + 4 * h) = ov;
      }
    if (h == 0) {
      float2 v; v.x = sidx ? mB : mA; v.y = sidx ? lB : lA;
      mlbuf[(size_t)(((z * 2 + bi) * 16 + hi)) * NSEQ + q0 + c] = v;
    }
  }
}

// ---------------- combine the two KV-parity partials ----------------
__global__ __launch_bounds__(256) void attn_combine(
    const bf16* __restrict__ O0, const bf16* __restrict__ O1,
    const float2* __restrict__ mlbuf, bf16* __restrict__ out)
{
  const int idx = blockIdx.x * 256 + threadIdx.x;
  const int e8 = idx * 8;                  // 8 elems/thread over 4096x1024
  const int qg  = e8 >> 10;                // global row 0..4095
  const int col = e8 & 1023;
  const int hi  = col >> 6;
  const int bi  = qg >> 11;
  const int q   = qg & 2047;
  const float2 ml0 = mlbuf[(size_t)(((0 * 2 + bi) * 16 + hi)) * NSEQ + q];
  const float2 ml1 = mlbuf[(size_t)(((1 * 2 + bi) * 16 + hi)) * NSEQ + q];
  const float M = fmaxf(ml0.x, ml1.x);
  const float w0 = __builtin_amdgcn_exp2f((ml0.x - M) * LOG2E);
  const float w1 = __builtin_amdgcn_exp2f((ml1.x - M) * LOG2E);
  const float dinv = 1.f / (w0 * ml0.y + w1 * ml1.y);
  const float s0 = w0 * dinv, s1 = w1 * dinv;
  bf16x8 a = *(const bf16x8*)(O0 + e8);
  bf16x8 b = *(const bf16x8*)(O1 + e8);
  bf16x8 o;
#pragma unroll
  for (int e = 0; e < 8; ++e)
    o[e] = (bf16)(s0 * (float)a[e] + s1 * (float)b[e]);
  *(bf16x8*)(out + e8) = o;
}

// ---------------- launch ----------------
extern "C" void kernel_launch(void* const* d_in, const int* in_sizes, int n_in,
                              void* d_out, int out_size, void* d_ws, size_t ws_size,
                              hipStream_t stream) {
  const void* x   = d_in[0];   // [2,2048,1024]
  const void* Wq  = d_in[1];   // [1024,1024]
  const void* Wkv = d_in[2];   // [1024,2048]
  const void* Wo  = d_in[3];   // [1024,1024]

  char* ws = (char*)d_ws;
  int*    flag  = (int*)ws;                                     //   4 KiB
  bf16*   xb    = (bf16*)(ws + (4ull << 10));                   //   8 MiB
  bf16*   WqkvT = (bf16*)(ws + (4ull << 10) + (8ull  << 20));   //   6 MiB
  bf16*   WoT   = (bf16*)(ws + (4ull << 10) + (14ull << 20));   //   2 MiB
  bf16*   QKVb  = (bf16*)(ws + (4ull << 10) + (16ull << 20));   //  24 MiB
  // Buffer reuse (sequencing makes each safe):
  bf16*   Opart0 = xb;                        // xb dead after QKV proj
  bf16*   Opart1 = (bf16*)d_out;              // overwritten by final O-proj
  float2* mlbuf  = (float2*)WqkvT;            // WqkvT dead after QKV proj (1 MiB used)
  bf16*   AOb    = QKVb;                      // QKVb dead after attn

  detect_dtype<<<1, 256, 0, stream>>>((const uint32_t*)x, flag);
  convert_x<<<4194304 / 8 / 256, 256, 0, stream>>>(x, xb, 4194304, flag);

  const dim3 tb(32, 8);
  transpose_conv<<<dim3(1024 / 32, 1024 / 32), tb, 0, stream>>>(Wq,  WqkvT,                1024, 1024, flag);
  transpose_conv<<<dim3(2048 / 32, 1024 / 32), tb, 0, stream>>>(Wkv, WqkvT + 1024 * 1024,  1024, 2048, flag);
  transpose_conv<<<dim3(1024 / 32, 1024 / 32), tb, 0, stream>>>(Wo,  WoT,                  1024, 1024, flag);

  // fused QKV projection: x @ [Wq | Wkv]
  gemm_bt<<<dim3(3072 / 128, 4096 / 128), 256, 0, stream>>>(xb, WqkvT, QKVb, 4096, 3072, 1024, nullptr);

  attn_fwd<<<dim3(16, 32, 2), 128, 0, stream>>>(QKVb, Opart0, Opart1, mlbuf);
  attn_combine<<<4194304 / 8 / 256, 256, 0, stream>>>(Opart0, Opart1, mlbuf, AOb);

  gemm_bt<<<dim3(1024 / 128, 4096 / 128), 256, 0, stream>>>(AOb, WoT, d_out, 4096, 1024, 1024, flag);
}

// Round 12
// 150.715 us; speedup vs baseline: 1.1224x; 1.1224x over previous
//
#include <hip/hip_runtime.h>
#include <stdint.h>
#include <stddef.h>

// Attention_50886772523162: x[2,2048,1024] -> causal MHA (16 heads, hd=64) -> out
// dtype (fp32 vs bf16) detected at runtime; compute bf16 MFMA, fp32 accum.
// Pipeline: detect -> convert x -> transpose weights (Wq|Wkv fused) ->
//           QKV proj (one GEMM) -> flash attn (balanced strips, SHARED per-tile
//           K/V fragments, tree reductions) -> O proj.
// NOTE: raw v_permlane32_swap_b32 inline asm caused NaN (R5) — blacklisted.
// NOTE: R7: causal imbalance (not scattered loads) caused the 2x; balance via
//       complementary strips (P, 63-P).
// NOTE: R9/R10/R11: per-CU unit throughput is ~constant (~1.7 units/us/CU)
//       regardless of resident waves => LDS pipe is the shared bottleneck.
//       This round: K/V fragment reads hoisted + shared across both strips
//       (-33% LDS reads); serial max/sum chains -> pairwise trees.

typedef __bf16 bf16;
typedef __bf16 bf16x8 __attribute__((ext_vector_type(8)));
typedef __bf16 bf16x4 __attribute__((ext_vector_type(4)));
typedef __bf16 bf16x2 __attribute__((ext_vector_type(2)));
typedef float  f32x4  __attribute__((ext_vector_type(4)));
typedef float  f32x16 __attribute__((ext_vector_type(16)));

#define NSEQ 2048
#define DM   1024
#define HD   64
#define QKVS 3072          // fused QKV row stride
#define LOG2E 1.44269504f

#define GLD16(g, l) __builtin_amdgcn_global_load_lds(                         \
    (const __attribute__((address_space(1))) void*)(g),                       \
    (__attribute__((address_space(3))) void*)(l), 16, 0, 0)

// ---------------- dtype detection ----------------
__global__ void detect_dtype(const uint32_t* __restrict__ x, int* __restrict__ flag) {
  __shared__ int cnt;
  if (threadIdx.x == 0) cnt = 0;
  __syncthreads();
  int c = 0;
  for (int i = threadIdx.x; i < 4096; i += 256) {
    uint32_t e = (x[i] >> 7) & 0xFF;
    if (e >= 110 && e <= 132) c++;
  }
  atomicAdd(&cnt, c);
  __syncthreads();
  if (threadIdx.x == 0) *flag = (cnt > 2048) ? 1 : 0;   // 1 = bf16 data
}

// ---------------- x -> canonical bf16 ----------------
__global__ __launch_bounds__(256) void convert_x(
    const void* __restrict__ in, bf16* __restrict__ out, int n,
    const int* __restrict__ flagp) {
  const int flag = *flagp;
  const int i = (blockIdx.x * 256 + threadIdx.x) * 8;
  if (i >= n) return;
  if (flag) {
    *(bf16x8*)(out + i) = *(const bf16x8*)((const bf16*)in + i);
  } else {
    const float* f = (const float*)in;
    bf16x8 v;
#pragma unroll
    for (int e = 0; e < 8; ++e) v[e] = (bf16)f[i + e];
    *(bf16x8*)(out + i) = v;
  }
}

// ---------------- weight transpose(+convert): in[K][N] -> out[N][K] ----------------
__global__ void transpose_conv(const void* __restrict__ in, bf16* __restrict__ out,
                               int K, int N, const int* __restrict__ flagp) {
  __shared__ bf16 tile[32][33];
  const int flag = *flagp;
  const int k0 = blockIdx.y * 32, n0 = blockIdx.x * 32;
  const int tx = threadIdx.x, ty = threadIdx.y;
  if (flag) {
    const bf16* p = (const bf16*)in;
#pragma unroll
    for (int i = ty; i < 32; i += 8)
      tile[i][tx] = p[(size_t)(k0 + i) * N + n0 + tx];
  } else {
    const float* p = (const float*)in;
#pragma unroll
    for (int i = ty; i < 32; i += 8)
      tile[i][tx] = (bf16)p[(size_t)(k0 + i) * N + n0 + tx];
  }
  __syncthreads();
#pragma unroll
  for (int i = ty; i < 32; i += 8)
    out[(size_t)(n0 + i) * K + k0 + tx] = tile[tx][i];
}

// ---------------- GEMM: C[M][N] = A[M][K] * Bt[N][K]^T ----------------
// 128x128 tile, BK=64, 4 waves (2x2), mfma_f32_16x16x32_bf16.
// Staging via global_load_lds (16B/lane, linear LDS dest, pre-swizzled source).
__global__ __launch_bounds__(256) void gemm_bt(
    const bf16* __restrict__ A, const bf16* __restrict__ Bt,
    void* __restrict__ C, int M, int N, int K, const int* flagp)
{
  __shared__ bf16 As[128][64];
  __shared__ bf16 Bs[128][64];
  const int tid  = threadIdx.x;
  const int wave = tid >> 6, lane = tid & 63;
  const int fr = lane & 15, fg = lane >> 4;
  const int m0 = blockIdx.y * 128, n0 = blockIdx.x * 128;
  const int wr = (wave >> 1) * 64, wc = (wave & 1) * 64;
  const int lrow = lane >> 3;                    // row within 8-row chunk
  const int lcol = 8 * ((lane & 7) ^ lrow);      // pre-swizzled source col (elems)

  f32x4 acc[4][4] = {};

  for (int kt = 0; kt < K; kt += 64) {
    __syncthreads();                              // protect prev-iter reads
#pragma unroll
    for (int p = 0; p < 4; ++p) {
      const int chunk = wave * 4 + p;             // 8 rows per chunk
      const int r = chunk * 8 + lrow;
      GLD16(A  + (size_t)(m0 + r) * K + kt + lcol, &As[chunk * 8][0]);
      GLD16(Bt + (size_t)(n0 + r) * K + kt + lcol, &Bs[chunk * 8][0]);
    }
    __syncthreads();                              // vmcnt(0) drain + barrier
#pragma unroll
    for (int s = 0; s < 2; ++s) {
      bf16x8 af[4], bfr[4];
#pragma unroll
      for (int i = 0; i < 4; ++i) {
        const int ar = wr + i * 16 + fr;
        af[i]  = *(const bf16x8*)((const char*)&As[ar][0] +
                   ((s * 64 + fg * 16) ^ ((ar & 7) << 4)));
        const int br = wc + i * 16 + fr;
        bfr[i] = *(const bf16x8*)((const char*)&Bs[br][0] +
                   ((s * 64 + fg * 16) ^ ((br & 7) << 4)));
      }
#pragma unroll
      for (int i = 0; i < 4; ++i)
#pragma unroll
        for (int j = 0; j < 4; ++j)
          acc[i][j] = __builtin_amdgcn_mfma_f32_16x16x32_bf16(
              af[i], bfr[j], acc[i][j], 0, 0, 0);
    }
  }
  const int crow = m0 + wr + fg * 4;
  const int ccol = n0 + wc + fr;
  const int as_bf16 = flagp ? *flagp : 1;
  if (as_bf16) {
    bf16* Cb = (bf16*)C;
#pragma unroll
    for (int i = 0; i < 4; ++i)
#pragma unroll
      for (int j = 0; j < 4; ++j)
#pragma unroll
        for (int r = 0; r < 4; ++r)
          Cb[(size_t)(crow + i * 16 + r) * N + ccol + j * 16] = (bf16)acc[i][j][r];
  } else {
    float* Cf = (float*)C;
#pragma unroll
    for (int i = 0; i < 4; ++i)
#pragma unroll
      for (int j = 0; j < 4; ++j)
#pragma unroll
        for (int r = 0; r < 4; ++r)
          Cf[(size_t)(crow + i * 16 + r) * N + ccol + j * 16] = acc[i][j][r];
  }
}

// ---------------- causal flash attention, balanced strips ----------------
// QKV: [B*N][3072] rows = (Q | K | V), head col offset hi*64.
// Block = 2 waves (128 threads); grid 16 pairs x 32 bh = 512 blocks.
// Wave owns strips sA = 2*pair+wave and sB = 63-sA (32 q-rows each).
// K/V MFMA fragments are strip-independent -> loaded ONCE per tile and shared
// by both strip computations (-33% LDS reads vs R9).
static __device__ inline uint32_t pk2(float a, float b) {
  bf16x2 t; t[0] = (bf16)a; t[1] = (bf16)b;
  return __builtin_bit_cast(uint32_t, t);
}

// One strip x one KV tile using pre-loaded K/V fragments.
static __device__ __forceinline__ void strip_compute(
    const bf16x8 (&kf)[2][4], const bf16x8 (&vf)[2][2][2],
    const bf16x8 (&qf)[4], f32x16 (&oacc)[2], float& m, float& l,
    const int j0, const int q0, const int c, const int h)
{
  const int qrow = q0 + c;
  const int blkmax = (j0 + 32 <= q0 + 31) ? 2 : 1;

  f32x16 sv[2];
  __builtin_amdgcn_s_setprio(1);
#pragma unroll
  for (int blk = 0; blk < 2; ++blk)
    if (blk < blkmax) {
      f32x16 a = {};
#pragma unroll
      for (int ks = 0; ks < 4; ++ks)
        a = __builtin_amdgcn_mfma_f32_32x32x16_bf16(kf[blk][ks], qf[ks], a, 0, 0, 0);
      sv[blk] = a;
    }
  __builtin_amdgcn_s_setprio(0);

  if (j0 + 63 > q0) {                       // causal mask (raw-S domain)
#pragma unroll
    for (int blk = 0; blk < 2; ++blk)
      if (blk < blkmax) {
        const int kvb = j0 + blk * 32 + 4 * h;
#pragma unroll
        for (int r = 0; r < 16; ++r) {
          const int kv = kvb + (r & 3) + 8 * (r >> 2);
          if (kv > qrow) sv[blk][r] = -4.0e8f;
        }
      }
  }

  // online softmax, lane-local; defer-max (T13, THR=8); tree reductions
  float red[8];
#pragma unroll
  for (int i = 0; i < 8; ++i) {
    float a = fmaxf(sv[0][i], sv[0][i + 8]);
    if (blkmax == 2) a = fmaxf(a, fmaxf(sv[1][i], sv[1][i + 8]));
    red[i] = a;
  }
#pragma unroll
  for (int w = 4; w >= 1; w >>= 1)
#pragma unroll
    for (int i = 0; i < w; ++i) red[i] = fmaxf(red[i], red[i + w]);
  float tmax = red[0];
  tmax = fmaxf(tmax, __shfl_xor(tmax, 32));
  const float pmax = tmax * 0.125f;
  if (!__all(pmax - m <= 8.0f)) {
    const float mnew  = fmaxf(m, pmax);
    const float alpha = __builtin_amdgcn_exp2f((m - mnew) * LOG2E);
    m = mnew;
    l *= alpha;
#pragma unroll
    for (int db = 0; db < 2; ++db)
#pragma unroll
      for (int r = 0; r < 16; ++r) oacc[db][r] *= alpha;
  }
  const float km = 0.125f * LOG2E, kb = -m * LOG2E;
#pragma unroll
  for (int blk = 0; blk < 2; ++blk)
    if (blk < blkmax)
#pragma unroll
      for (int r = 0; r < 16; ++r)
        sv[blk][r] = __builtin_amdgcn_exp2f(__builtin_fmaf(sv[blk][r], km, kb));
  float sr[8];
#pragma unroll
  for (int i = 0; i < 8; ++i) {
    float a = sv[0][i] + sv[0][i + 8];
    if (blkmax == 2) a += sv[1][i] + sv[1][i + 8];
    sr[i] = a;
  }
#pragma unroll
  for (int w = 4; w >= 1; w >>= 1)
#pragma unroll
    for (int i = 0; i < w; ++i) sr[i] += sr[i + w];
  float sum = sr[0];
  sum += __shfl_xor(sum, 32);
  l += sum;

  // P redistribution (D-layout -> B-operand) + PV
#pragma unroll
  for (int blk = 0; blk < 2; ++blk)
    if (blk < blkmax) {
      uint32_t w[8], xw[8];
#pragma unroll
      for (int g = 0; g < 4; ++g) {
        w[2 * g]     = pk2(sv[blk][4 * g],     sv[blk][4 * g + 1]);
        w[2 * g + 1] = pk2(sv[blk][4 * g + 2], sv[blk][4 * g + 3]);
      }
#pragma unroll
      for (int i = 0; i < 8; ++i)
        xw[i] = (uint32_t)__shfl_xor((int)w[i], 32);
#pragma unroll
      for (int ks = 0; ks < 2; ++ks) {
        union { uint32_t u[4]; bf16x8 v; } pf;
        pf.u[0] = h ? xw[4 * ks + 2] : w[4 * ks];
        pf.u[1] = h ? xw[4 * ks + 3] : w[4 * ks + 1];
        pf.u[2] = h ? w[4 * ks + 2]  : xw[4 * ks];
        pf.u[3] = h ? w[4 * ks + 3]  : xw[4 * ks + 1];
        __builtin_amdgcn_s_setprio(1);
#pragma unroll
        for (int db = 0; db < 2; ++db)
          oacc[db] = __builtin_amdgcn_mfma_f32_32x32x16_bf16(
              vf[blk][ks][db], pf.v, oacc[db], 0, 0, 0);
        __builtin_amdgcn_s_setprio(0);
      }
    }
}

__global__ __launch_bounds__(128) void attn_fwd(
    const bf16* __restrict__ QKV, bf16* __restrict__ O)
{
  __shared__ bf16 Ks[2][64][64];   // K tiles [kv][d], rows XOR-swizzled
  __shared__ bf16 Vt[2][64][64];   // V^T tiles [d][kv], rows XOR-swizzled

  const int pr = blockIdx.x;       // pair index 0..15
  const int bh = blockIdx.y;
  const int bi = bh >> 4, hi = bh & 15;
  const int tid = threadIdx.x, wave = tid >> 6, lane = tid & 63;
  const int c = lane & 31, h = lane >> 5;

  const bf16* qptr = QKV + (size_t)bi * NSEQ * QKVS + hi * HD;
  const bf16* kptr = qptr + DM;
  const bf16* vptr = qptr + 2 * DM;

  // complementary strips (32 q-rows each)
  const int sA = 2 * pr + wave, sB = 63 - sA;
  const int q0A = sA * 32, q0B = sB * 32;

  bf16x8 qfA[4], qfB[4];
#pragma unroll
  for (int ks = 0; ks < 4; ++ks) {
    qfA[ks] = *(const bf16x8*)(qptr + (size_t)(q0A + c) * QKVS + ks * 16 + h * 8);
    qfB[ks] = *(const bf16x8*)(qptr + (size_t)(q0B + c) * QKVS + ks * 16 + h * 8);
  }

  f32x16 oaccA[2] = {}, oaccB[2] = {};
  float mA = -1e30f, lA = 0.f, mB = -1e30f, lB = 0.f;

  // K staging: 128 threads cover 16 rows x 8 chunks per pass, 4 passes
  const int srow = tid >> 3, sch = tid & 7;
  const int koff = (sch * 16) ^ ((srow & 7) << 4);   // (row+16p)&7 == row&7
  // V staging: thread covers 4 kv rows x 8 d cols (64x64 in one pass)
  const int kvg = (tid & 15) * 4, dg = (tid >> 4) * 8;

  bf16x8 kpre[4], vpre[4];      // prefetch regs (loaded t-1, published top of t+1)

  const int ntil = 32 - pr;     // tiles covering strip B (the larger)

  // prologue: tile0 -> LDS buf0 directly; tile1 -> regs
  {
#pragma unroll
    for (int p = 0; p < 4; ++p)
      kpre[p] = *(const bf16x8*)(kptr + (size_t)(srow + 16 * p) * QKVS + sch * 8);
#pragma unroll
    for (int i = 0; i < 4; ++i)
      vpre[i] = *(const bf16x8*)(vptr + (size_t)(kvg + i) * QKVS + dg);
#pragma unroll
    for (int p = 0; p < 4; ++p)
      *(bf16x8*)((char*)&Ks[0][srow + 16 * p][0] + koff) = kpre[p];
#pragma unroll
    for (int e = 0; e < 8; ++e) {
      const int d = dg + e;
      bf16x4 w; w[0] = vpre[0][e]; w[1] = vpre[1][e];
      w[2] = vpre[2][e]; w[3] = vpre[3][e];
      *(bf16x4*)((char*)&Vt[0][d][0] + ((2 * kvg) ^ ((d & 7) << 4))) = w;
    }
#pragma unroll
    for (int p = 0; p < 4; ++p)
      kpre[p] = *(const bf16x8*)(kptr + (size_t)(64 + srow + 16 * p) * QKVS + sch * 8);
#pragma unroll
    for (int i = 0; i < 4; ++i)
      vpre[i] = *(const bf16x8*)(vptr + (size_t)(64 + kvg + i) * QKVS + dg);
  }
  __syncthreads();

  for (int t = 0; t < ntil; ++t) {
    const int cur = t & 1;
    const int j0 = t * 64;

    // top: publish tile t+1 into the other buffer (its readers finished
    // before the barrier that ended iter t-1)
    if (t + 1 < ntil) {
      const int nb = cur ^ 1;
#pragma unroll
      for (int p = 0; p < 4; ++p)
        *(bf16x8*)((char*)&Ks[nb][srow + 16 * p][0] + koff) = kpre[p];
#pragma unroll
      for (int e = 0; e < 8; ++e) {
        const int d = dg + e;
        bf16x4 w; w[0] = vpre[0][e]; w[1] = vpre[1][e];
        w[2] = vpre[2][e]; w[3] = vpre[3][e];
        *(bf16x4*)((char*)&Vt[nb][d][0] + ((2 * kvg) ^ ((d & 7) << 4))) = w;
      }
    }
    // issue tile t+2 loads (land during next iteration's compute)
    if (t + 2 < ntil) {
      const int jn = j0 + 128;
#pragma unroll
      for (int p = 0; p < 4; ++p)
        kpre[p] = *(const bf16x8*)(kptr + (size_t)(jn + srow + 16 * p) * QKVS + sch * 8);
#pragma unroll
      for (int i = 0; i < 4; ++i)
        vpre[i] = *(const bf16x8*)(vptr + (size_t)(jn + kvg + i) * QKVS + dg);
    }

    // shared per-tile K/V fragments (strip-independent addresses)
    bf16x8 kf[2][4], vf[2][2][2];
#pragma unroll
    for (int blk = 0; blk < 2; ++blk) {
      const int krow = blk * 32 + c;
#pragma unroll
      for (int ks = 0; ks < 4; ++ks)
        kf[blk][ks] = *(const bf16x8*)((const char*)&Ks[cur][krow][0] +
                       ((ks * 32 + h * 16) ^ ((krow & 7) << 4)));
#pragma unroll
      for (int ks = 0; ks < 2; ++ks)
#pragma unroll
        for (int db = 0; db < 2; ++db) {
          const int vrow = db * 32 + c;
          vf[blk][ks][db] = *(const bf16x8*)((const char*)&Vt[cur][vrow][0] +
                             ((blk * 64 + ks * 32 + h * 16) ^ ((vrow & 7) << 4)));
        }
    }

    // strip B (large) on every staged tile; strip A while t <= pr
    strip_compute(kf, vf, qfB, oaccB, mB, lB, j0, q0B, c, h);
    if (j0 <= q0A + 31)
      strip_compute(kf, vf, qfA, oaccA, mA, lA, j0, q0A, c, h);

    __syncthreads();              // single barrier per tile
  }

  // epilogue: O[q][d] = oacc^T / l   (all lane-local)
#pragma unroll
  for (int sidx = 0; sidx < 2; ++sidx) {
    const f32x16* oacc = sidx ? oaccB : oaccA;
    const float linv = 1.f / (sidx ? lB : lA);
    const int q0 = sidx ? q0B : q0A;
    bf16* obase = O + (size_t)bi * NSEQ * DM + (size_t)hi * HD +
                  (size_t)(q0 + c) * DM;
#pragma unroll
    for (int db = 0; db < 2; ++db)
#pragma unroll
      for (int g = 0; g < 4; ++g) {
        bf16x4 ov;
#pragma unroll
        for (int j = 0; j < 4; ++j) ov[j] = (bf16)(oacc[db][4 * g + j] * linv);
        *(bf16x4*)(obase + db * 32 + 8 * g + 4 * h) = ov;
      }
  }
}

// ---------------- launch ----------------
extern "C" void kernel_launch(void* const* d_in, const int* in_sizes, int n_in,
                              void* d_out, int out_size, void* d_ws, size_t ws_size,
                              hipStream_t stream) {
  const void* x   = d_in[0];   // [2,2048,1024]
  const void* Wq  = d_in[1];   // [1024,1024]
  const void* Wkv = d_in[2];   // [1024,2048]
  const void* Wo  = d_in[3];   // [1024,1024]

  char* ws = (char*)d_ws;
  int*  flag   = (int*)ws;                                      //   4 KiB
  bf16* xb     = (bf16*)(ws + (4ull << 10));                    //   8 MiB
  bf16* WqkvT  = (bf16*)(ws + (4ull << 10) + (8ull  << 20));    //   6 MiB [3072][1024]
  bf16* WoT    = (bf16*)(ws + (4ull << 10) + (14ull << 20));    //   2 MiB [1024][1024]
  bf16* QKVb   = (bf16*)(ws + (4ull << 10) + (16ull << 20));    //  24 MiB [4096][3072]
  bf16* AOb    = xb;  // x dead after projection; reuse

  detect_dtype<<<1, 256, 0, stream>>>((const uint32_t*)x, flag);
  convert_x<<<4194304 / 8 / 256, 256, 0, stream>>>(x, xb, 4194304, flag);

  const dim3 tb(32, 8);
  transpose_conv<<<dim3(1024 / 32, 1024 / 32), tb, 0, stream>>>(Wq,  WqkvT,                1024, 1024, flag);
  transpose_conv<<<dim3(2048 / 32, 1024 / 32), tb, 0, stream>>>(Wkv, WqkvT + 1024 * 1024,  1024, 2048, flag);
  transpose_conv<<<dim3(1024 / 32, 1024 / 32), tb, 0, stream>>>(Wo,  WoT,                  1024, 1024, flag);

  // fused QKV projection: x @ [Wq | Wkv]
  gemm_bt<<<dim3(3072 / 128, 4096 / 128), 256, 0, stream>>>(xb, WqkvT, QKVb, 4096, 3072, 1024, nullptr);

  attn_fwd<<<dim3(16, 32), 128, 0, stream>>>(QKVb, AOb);

  gemm_bt<<<dim3(1024 / 128, 4096 / 128), 256, 0, stream>>>(AOb, WoT, d_out, 4096, 1024, 1024, flag);
}